// Round 1
// baseline (27.564 us; speedup 1.0000x reference)
//
#include <hip/hip_runtime.h>

// out[b,o] = sum_{i,n} (Ps*tanh(k*(x + Ec*bm)) + bias) * coef
// bm = 1 - 0.4*(1 - sigmoid(10*(x_b - x_{b-1}))) * sigmoid(10*(-x - Ec))
// (switch_up cancels algebraically: target = 1 - 2*switch_lo)
//
// tanh(a) = 1 - 2/(exp(2a)+1)  ->  out = base[o] - 2 * sum pc*r
//   base[o] = sum (Ps + bias)*coef   (batch-independent, block-reduced once)
//   pc = Ps*coef, r = rcp(exp2(k2*inner)+1), k2 = 2*log2(e)*k

#define GATE_C 14.426950408889634f   // 10*log2(e)
#define TANH_C 2.8853900817779268f   // 2*log2(e)

constexpr int B = 512, I = 128, O = 64, NB = 8, BT = 32;

__global__ __launch_bounds__(256) void fe_main(
    const float* __restrict__ x, const float* __restrict__ k,
    const float* __restrict__ Ec, const float* __restrict__ Ps,
    const float* __restrict__ bias, const float* __restrict__ coef,
    float* __restrict__ out)
{
  __shared__ float4 p_lds[I * NB];        // {Ec, Ec*GATE_C, k*TANH_C, Ps*coef}, [i][n]
  __shared__ float2 xc_lds[BT][I + 1];    // {x, c}; +1 pad -> conflict-free b-strided reads
  __shared__ float red[4];

  const int tid = threadIdx.x;
  const int o  = blockIdx.y;
  const int b0 = blockIdx.x * BT;

  // ---- stage packed params for this o, accumulate base[o] partial ----
  float pbase = 0.f;
  for (int e = tid; e < I * NB; e += 256) {
    const int i = e >> 3, n = e & 7;
    const int g = (i * O + o) * NB + n;
    const float ec = Ec[g], kk = k[g], ps = Ps[g], cf = coef[g], bs = bias[g];
    const float pc = ps * cf;
    p_lds[e] = make_float4(ec, ec * GATE_C, kk * TANH_C, pc);
    pbase += fmaf(bs, cf, pc);
  }

  // ---- stage {x, c} for this batch tile ----
  for (int e = tid; e < BT * I; e += 256) {
    const int bl = e >> 7, i = e & 127;
    const int bg = b0 + bl;
    const float xv = x[bg * I + i];
    const float pv = (bg == 0) ? 0.f : x[(bg - 1) * I + i];
    // c = -0.4 * (1 - sigmoid(10*dx)) = -0.4 * sigmoid(-10*dx)
    const float c = -0.4f * __builtin_amdgcn_rcpf(
        1.f + __builtin_amdgcn_exp2f(GATE_C * (xv - pv)));
    xc_lds[bl][i] = make_float2(xv, c);
  }

  // base partial: full-wave butterfly, one partial per wave
  #pragma unroll
  for (int m = 1; m < 64; m <<= 1) pbase += __shfl_xor(pbase, m);
  if ((tid & 63) == 0) red[tid >> 6] = pbase;
  __syncthreads();

  // ---- main loop: thread = (b_local, n), reduce over i ----
  const int bl = tid >> 3, n = tid & 7;
  const float4* __restrict__ prow = p_lds + n;     // prow[i*8] = p_lds[i*8+n]
  const float2* __restrict__ xrow = &xc_lds[bl][0];

  float acc = 0.f;
  #pragma unroll 4
  for (int i = 0; i < I; ++i) {
    const float2 xc = xrow[i];          // broadcast across 8 n-lanes
    const float4 p  = prow[i * 8];      // broadcast across 8 b-lanes, 32 banks
    // crossed_neg = 1/(1 + exp(10*(x+Ec))) = rcp(1 + exp2(GATE_C*x + GATE_C*Ec))
    const float sg = __builtin_amdgcn_rcpf(
        1.f + __builtin_amdgcn_exp2f(fmaf(xc.x, GATE_C, p.y)));
    const float bm    = fmaf(xc.y, sg, 1.f);       // 1 + c*sg
    const float inner = fmaf(p.x, bm, xc.x);       // x + Ec*bm
    const float r = __builtin_amdgcn_rcpf(
        1.f + __builtin_amdgcn_exp2f(p.z * inner)); // rcp(exp(2a)+1)
    acc = fmaf(p.w, r, acc);                        // sum pc*r
  }

  // reduce over the 8 n-lanes (contiguous within wave)
  acc += __shfl_xor(acc, 1);
  acc += __shfl_xor(acc, 2);
  acc += __shfl_xor(acc, 4);

  if (n == 0) {
    const float base = red[0] + red[1] + red[2] + red[3];
    out[(b0 + bl) * O + o] = fmaf(-2.f, acc, base);
  }
}

extern "C" void kernel_launch(void* const* d_in, const int* in_sizes, int n_in,
                              void* d_out, int out_size, void* d_ws, size_t ws_size,
                              hipStream_t stream) {
  const float* x    = (const float*)d_in[0];
  const float* k    = (const float*)d_in[1];
  const float* Ec   = (const float*)d_in[2];
  const float* Ps   = (const float*)d_in[3];
  const float* bias = (const float*)d_in[4];
  const float* coef = (const float*)d_in[5];
  float* out = (float*)d_out;

  dim3 grid(B / BT, O);   // 16 batch tiles x 64 output channels
  fe_main<<<grid, 256, 0, stream>>>(x, k, Ec, Ps, bias, coef, out);
}